// Round 5
// baseline (105.426 us; speedup 1.0000x reference)
//
#include <hip/hip_runtime.h>

// BilinearFullSymLoss: B=32 samples, grid [B,2,512,512] fp32.
// Per sample: masked sum of (delta0*sy + delta1*sx)^2 / count, then mean over B.
// Mask excludes the jnp.roll wrap region -> plain offset loads, no wrapping.
// neg branch simplified: d_neg = fx*a2 + (1-fx)*a1 - fy*s_top - (1-fy)*s_bot.
//
// Round 5: fused reduction. zero_out<<<1,64>>> (plain store, graph-safe) then
// stage1 does one device-scope atomicAdd per block (1024 same-address atomics,
// sub-us). Stage1 geometry identical to round 4: register row-chaining
// (pos: b(i)=a(i+1); neg: s_bot(i)=s_top(i+1)), uniform control flow (tail
// chunk re-anchored at cols-8, cndmask on duplicated lanes), 16 rows/block.

#define GH 512
#define GW 512
#define GB 32
#define CH (GH * GW)
#define RPB 16
#define BLOCK 256
#define NBLK_X (GH / RPB)        // 32

struct F4U { float x, y, z, w; };   // align 4 -> dword-aligned 16B loads ok

__device__ __forceinline__ void load9(const float* __restrict__ p, float* o) {
    const F4U a = *(const F4U*)p;
    const F4U b = *(const F4U*)(p + 4);
    o[0]=a.x; o[1]=a.y; o[2]=a.z; o[3]=a.w;
    o[4]=b.x; o[5]=b.y; o[6]=b.z; o[7]=b.w;
    o[8] = p[8];
}

__device__ __forceinline__ void load8(const float* __restrict__ p, float* o) {
    const F4U a = *(const F4U*)p;
    const F4U b = *(const F4U*)(p + 4);
    o[0]=a.x; o[1]=a.y; o[2]=a.z; o[3]=a.w;
    o[4]=b.x; o[5]=b.y; o[6]=b.z; o[7]=b.w;
}

__global__ void zero_out(float* __restrict__ out) {
    if (threadIdx.x == 0) out[0] = 0.0f;
}

__global__ __launch_bounds__(BLOCK) void bilinear_sym_loss_stage1(
    const float* __restrict__ grid,
    const float* __restrict__ gt,   // [B,2]  (gt_x, gt_y)
    const float* __restrict__ gd,   // [B,2]  (sx, sy)
    float* __restrict__ out)
{
    const int b = blockIdx.y;

    const float dx = -10.0f * gt[b * 2 + 0];
    const float dy =  10.0f * gt[b * 2 + 1];
    const float sx = gd[b * 2 + 0];
    const float sy = gd[b * 2 + 1];

    const float dy1f = floorf(dy);
    const float dx1f = floorf(dx);
    const int dy1 = (int)dy1f;
    const int dx1 = (int)dx1f;
    const float fy = dy - dy1f;
    const float fx = dx - dx1f;

    const bool pos = dx > 0.0f;
    const int rows = GH - dy1 - 1;                        // 506..511
    const int cols = pos ? (GW - dx1 - 1) : (GW + dx1);   // 507..509

    const float omfx = 1.0f - fx;
    const float omfy = 1.0f - fy;
    const float w22 = fx * fy;
    const float w21 = fx * omfy;
    const float w12 = omfx * fy;
    const float w11 = omfx * omfy;

    const float* __restrict__ g0 = grid + (size_t)b * 2u * CH;

    const int tid = threadIdx.x;
    const int cc = tid & 63;          // column chunk (8 cols each)
    const int rg = tid >> 6;          // row group (wave-uniform)
    const int i0 = blockIdx.x * RPB + rg * 4;

    // Last chunk re-anchors at cols-8; kmin masks elements already counted
    // by the previous chunk. All lanes then run identical vector code.
    int j0 = cc << 3;
    int kmin = 0;
    if (j0 > cols - 8) { kmin = j0 - (cols - 8); j0 = cols - 8; }

    float acc = 0.0f;

    if (pos) {
        if (i0 < rows) {   // wave-uniform
            const float* pa0 = g0 + (i0 + dy1) * GW + dx1 + j0;   // shifted rows, ch0
            const float* pc0 = g0 + i0 * GW + j0;                 // center rows, ch0
            float P0[9], P1[9];
            load9(pa0, P0);
            load9(pa0 + CH, P1);
            #pragma unroll
            for (int r = 0; r < 4; ++r) {
                const int i = i0 + r;
                if (i >= rows) break;   // wave-uniform
                float B0[9], B1[9], C0[8], C1[8];
                load9(pa0 + (r + 1) * GW, B0);
                load9(pa0 + (r + 1) * GW + CH, B1);
                load8(pc0 + r * GW, C0);
                load8(pc0 + r * GW + CH, C1);
                #pragma unroll
                for (int k = 0; k < 8; ++k) {
                    float t0 = w11 * P0[k];
                    t0 = fmaf(w21, P0[k + 1], t0);
                    t0 = fmaf(w12, B0[k], t0);
                    t0 = fmaf(w22, B0[k + 1], t0);
                    const float d0 = C0[k] - t0;
                    float t1 = w11 * P1[k];
                    t1 = fmaf(w21, P1[k + 1], t1);
                    t1 = fmaf(w12, B1[k], t1);
                    t1 = fmaf(w22, B1[k + 1], t1);
                    const float d1 = C1[k] - t1;
                    float v = fmaf(d0, sy, d1 * sx);
                    v = (k >= kmin) ? v : 0.0f;
                    acc = fmaf(v, v, acc);
                }
                #pragma unroll
                for (int k = 0; k < 9; ++k) { P0[k] = B0[k]; P1[k] = B1[k]; }
            }
        }
    } else {
        if (i0 < rows) {
            const int jo = -dx1;   // 3..5
            const float* pt0 = g0 + i0 * GW + jo + j0;             // s_top row for i0
            const float* pa0 = g0 + (i0 + dy1 + 1) * GW + j0;      // anchor rows
            float T0[8], T1[8];
            load8(pt0, T0);
            load8(pt0 + CH, T1);
            #pragma unroll
            for (int r = 0; r < 4; ++r) {
                const int i = i0 + r;
                if (i >= rows) break;
                float S0[8], S1[8], A0[9], A1[9];
                load8(pt0 + (r + 1) * GW, S0);
                load8(pt0 + (r + 1) * GW + CH, S1);
                load9(pa0 + r * GW, A0);
                load9(pa0 + r * GW + CH, A1);
                #pragma unroll
                for (int k = 0; k < 8; ++k) {
                    float d0 = fx * A0[k + 1];
                    d0 = fmaf(omfx, A0[k], d0);
                    d0 = fmaf(-fy, T0[k], d0);
                    d0 = fmaf(-omfy, S0[k], d0);
                    float d1 = fx * A1[k + 1];
                    d1 = fmaf(omfx, A1[k], d1);
                    d1 = fmaf(-fy, T1[k], d1);
                    d1 = fmaf(-omfy, S1[k], d1);
                    float v = fmaf(d0, sy, d1 * sx);
                    v = (k >= kmin) ? v : 0.0f;
                    acc = fmaf(v, v, acc);
                }
                #pragma unroll
                for (int k = 0; k < 8; ++k) { T0[k] = S0[k]; T1[k] = S1[k]; }
            }
        }
    }

    // Block reduction: wave64 shuffle, then LDS across the 4 waves.
    for (int off = 32; off > 0; off >>= 1)
        acc += __shfl_down(acc, off, 64);

    __shared__ float wave_sums[BLOCK / 64];
    const int lane = tid & 63;
    const int wid = tid >> 6;
    if (lane == 0) wave_sums[wid] = acc;
    __syncthreads();

    if (tid == 0) {
        const float s = wave_sums[0] + wave_sums[1] + wave_sums[2] + wave_sums[3];
        const float count = (float)rows * (float)cols;
        const float scale = 1.0f / (count * (float)GB);
        // Device-scope atomic (default on global memory) -> XCD-safe.
        atomicAdd(out, s * scale);
    }
}

extern "C" void kernel_launch(void* const* d_in, const int* in_sizes, int n_in,
                              void* d_out, int out_size, void* d_ws, size_t ws_size,
                              hipStream_t stream) {
    const float* grid = (const float*)d_in[0];
    const float* gt   = (const float*)d_in[1];
    const float* gd   = (const float*)d_in[2];
    float* out = (float*)d_out;

    zero_out<<<dim3(1), dim3(64), 0, stream>>>(out);
    dim3 grid1(NBLK_X, GB);
    bilinear_sym_loss_stage1<<<grid1, dim3(BLOCK), 0, stream>>>(grid, gt, gd, out);
}

// Round 6
// 99.329 us; speedup vs baseline: 1.0614x; 1.0614x over previous
//
#include <hip/hip_runtime.h>

// BilinearFullSymLoss: B=32 samples, grid [B,2,512,512] fp32.
// Per sample: masked sum of (delta0*sy + delta1*sx)^2 / count, then mean over B.
// Mask excludes the jnp.roll wrap region -> plain offset loads, no wrapping.
// neg branch simplified: d_neg = fx*a2 + (1-fx)*a1 - fy*s_top - (1-fy)*s_bot.
//
// Round 6: REVERT to round-4 structure (best measured: 98.7 us).
// Round-5's single-address device atomicAdd from 1024 blocks regressed ~7 us:
// cross-XCD cache-line ownership ping-pong serializes same-address atomics.
// Two-stage with disjoint partial stores avoids all coherence churn.
// Stage1: register row-chaining (pos: b(i)=a(i+1); neg: s_bot(i)=s_top(i+1)),
// uniform control flow (tail chunk re-anchored at cols-8, cndmask on
// duplicated lanes), 16 rows/block, 4-wide dword-aligned 16B loads.

#define GH 512
#define GW 512
#define GB 32
#define CH (GH * GW)
#define RPB 16
#define BLOCK 256
#define NBLK_X (GH / RPB)        // 32
#define NPART (NBLK_X * GB)      // 1024

struct F4U { float x, y, z, w; };   // align 4 -> dword-aligned 16B loads ok

__device__ __forceinline__ void load9(const float* __restrict__ p, float* o) {
    const F4U a = *(const F4U*)p;
    const F4U b = *(const F4U*)(p + 4);
    o[0]=a.x; o[1]=a.y; o[2]=a.z; o[3]=a.w;
    o[4]=b.x; o[5]=b.y; o[6]=b.z; o[7]=b.w;
    o[8] = p[8];
}

__device__ __forceinline__ void load8(const float* __restrict__ p, float* o) {
    const F4U a = *(const F4U*)p;
    const F4U b = *(const F4U*)(p + 4);
    o[0]=a.x; o[1]=a.y; o[2]=a.z; o[3]=a.w;
    o[4]=b.x; o[5]=b.y; o[6]=b.z; o[7]=b.w;
}

__global__ __launch_bounds__(BLOCK) void bilinear_sym_loss_stage1(
    const float* __restrict__ grid,
    const float* __restrict__ gt,   // [B,2]  (gt_x, gt_y)
    const float* __restrict__ gd,   // [B,2]  (sx, sy)
    float* __restrict__ partials)
{
    const int b = blockIdx.y;

    const float dx = -10.0f * gt[b * 2 + 0];
    const float dy =  10.0f * gt[b * 2 + 1];
    const float sx = gd[b * 2 + 0];
    const float sy = gd[b * 2 + 1];

    const float dy1f = floorf(dy);
    const float dx1f = floorf(dx);
    const int dy1 = (int)dy1f;
    const int dx1 = (int)dx1f;
    const float fy = dy - dy1f;
    const float fx = dx - dx1f;

    const bool pos = dx > 0.0f;
    const int rows = GH - dy1 - 1;                        // 506..511
    const int cols = pos ? (GW - dx1 - 1) : (GW + dx1);   // 507..509

    const float omfx = 1.0f - fx;
    const float omfy = 1.0f - fy;
    const float w22 = fx * fy;
    const float w21 = fx * omfy;
    const float w12 = omfx * fy;
    const float w11 = omfx * omfy;

    const float* __restrict__ g0 = grid + (size_t)b * 2u * CH;

    const int tid = threadIdx.x;
    const int cc = tid & 63;          // column chunk (8 cols each)
    const int rg = tid >> 6;          // row group (wave-uniform)
    const int i0 = blockIdx.x * RPB + rg * 4;

    // Last chunk re-anchors at cols-8; kmin masks elements already counted
    // by the previous chunk. All lanes then run identical vector code.
    int j0 = cc << 3;
    int kmin = 0;
    if (j0 > cols - 8) { kmin = j0 - (cols - 8); j0 = cols - 8; }

    float acc = 0.0f;

    if (pos) {
        if (i0 < rows) {   // wave-uniform
            const float* pa0 = g0 + (i0 + dy1) * GW + dx1 + j0;   // shifted rows, ch0
            const float* pc0 = g0 + i0 * GW + j0;                 // center rows, ch0
            float P0[9], P1[9];
            load9(pa0, P0);
            load9(pa0 + CH, P1);
            #pragma unroll
            for (int r = 0; r < 4; ++r) {
                const int i = i0 + r;
                if (i >= rows) break;   // wave-uniform
                float B0[9], B1[9], C0[8], C1[8];
                load9(pa0 + (r + 1) * GW, B0);
                load9(pa0 + (r + 1) * GW + CH, B1);
                load8(pc0 + r * GW, C0);
                load8(pc0 + r * GW + CH, C1);
                #pragma unroll
                for (int k = 0; k < 8; ++k) {
                    float t0 = w11 * P0[k];
                    t0 = fmaf(w21, P0[k + 1], t0);
                    t0 = fmaf(w12, B0[k], t0);
                    t0 = fmaf(w22, B0[k + 1], t0);
                    const float d0 = C0[k] - t0;
                    float t1 = w11 * P1[k];
                    t1 = fmaf(w21, P1[k + 1], t1);
                    t1 = fmaf(w12, B1[k], t1);
                    t1 = fmaf(w22, B1[k + 1], t1);
                    const float d1 = C1[k] - t1;
                    float v = fmaf(d0, sy, d1 * sx);
                    v = (k >= kmin) ? v : 0.0f;
                    acc = fmaf(v, v, acc);
                }
                #pragma unroll
                for (int k = 0; k < 9; ++k) { P0[k] = B0[k]; P1[k] = B1[k]; }
            }
        }
    } else {
        if (i0 < rows) {
            const int jo = -dx1;   // 3..5
            const float* pt0 = g0 + i0 * GW + jo + j0;             // s_top row for i0
            const float* pa0 = g0 + (i0 + dy1 + 1) * GW + j0;      // anchor rows
            float T0[8], T1[8];
            load8(pt0, T0);
            load8(pt0 + CH, T1);
            #pragma unroll
            for (int r = 0; r < 4; ++r) {
                const int i = i0 + r;
                if (i >= rows) break;
                float S0[8], S1[8], A0[9], A1[9];
                load8(pt0 + (r + 1) * GW, S0);
                load8(pt0 + (r + 1) * GW + CH, S1);
                load9(pa0 + r * GW, A0);
                load9(pa0 + r * GW + CH, A1);
                #pragma unroll
                for (int k = 0; k < 8; ++k) {
                    float d0 = fx * A0[k + 1];
                    d0 = fmaf(omfx, A0[k], d0);
                    d0 = fmaf(-fy, T0[k], d0);
                    d0 = fmaf(-omfy, S0[k], d0);
                    float d1 = fx * A1[k + 1];
                    d1 = fmaf(omfx, A1[k], d1);
                    d1 = fmaf(-fy, T1[k], d1);
                    d1 = fmaf(-omfy, S1[k], d1);
                    float v = fmaf(d0, sy, d1 * sx);
                    v = (k >= kmin) ? v : 0.0f;
                    acc = fmaf(v, v, acc);
                }
                #pragma unroll
                for (int k = 0; k < 8; ++k) { T0[k] = S0[k]; T1[k] = S1[k]; }
            }
        }
    }

    // Block reduction: wave64 shuffle, then LDS across the 4 waves.
    for (int off = 32; off > 0; off >>= 1)
        acc += __shfl_down(acc, off, 64);

    __shared__ float wave_sums[BLOCK / 64];
    const int lane = tid & 63;
    const int wid = tid >> 6;
    if (lane == 0) wave_sums[wid] = acc;
    __syncthreads();

    if (tid == 0) {
        const float s = wave_sums[0] + wave_sums[1] + wave_sums[2] + wave_sums[3];
        const float count = (float)rows * (float)cols;
        const float scale = 1.0f / (count * (float)GB);
        partials[b * NBLK_X + blockIdx.x] = s * scale;   // covers ws poison
    }
}

__global__ __launch_bounds__(BLOCK) void bilinear_sym_loss_stage2(
    const float* __restrict__ partials,
    float* __restrict__ out)
{
    const int tid = threadIdx.x;
    float acc = 0.0f;
    for (int i = tid; i < NPART; i += BLOCK)
        acc += partials[i];

    for (int off = 32; off > 0; off >>= 1)
        acc += __shfl_down(acc, off, 64);

    __shared__ float wave_sums[BLOCK / 64];
    const int lane = tid & 63;
    const int wid = tid >> 6;
    if (lane == 0) wave_sums[wid] = acc;
    __syncthreads();

    if (tid == 0)
        out[0] = wave_sums[0] + wave_sums[1] + wave_sums[2] + wave_sums[3];
}

extern "C" void kernel_launch(void* const* d_in, const int* in_sizes, int n_in,
                              void* d_out, int out_size, void* d_ws, size_t ws_size,
                              hipStream_t stream) {
    const float* grid = (const float*)d_in[0];
    const float* gt   = (const float*)d_in[1];
    const float* gd   = (const float*)d_in[2];
    float* out = (float*)d_out;
    float* partials = (float*)d_ws;  // NPART floats = 4 KiB

    dim3 grid1(NBLK_X, GB);
    bilinear_sym_loss_stage1<<<grid1, dim3(BLOCK), 0, stream>>>(grid, gt, gd, partials);
    bilinear_sym_loss_stage2<<<dim3(1), dim3(BLOCK), 0, stream>>>(partials, out);
}